// Round 2
// baseline (506.219 us; speedup 1.0000x reference)
//
#include <hip/hip_runtime.h>
#include <cstdint>

// Problem dims (fixed by reference)
#define B_  16
#define N_  32
#define L_  2048
#define D_  16
#define M_  32
#define K_  3
#define W_  2046   // (L - K)/STRIDE + 1

// Block: 256 threads = 64 w-positions (fast, coalesced) x 4 m values.
// Grid: (ceil(W/64)=32, M/4=8, B=16).
// LDS: weights for the block's 4 m's, pre-scaled by 1/32 (uniform softmax
// routing weight), laid out [ml][n][k][x*4+d] so the inner loop reads one
// float4 per (n,k,x) — wave-uniform address => broadcast, no bank conflicts.
__global__ __launch_bounds__(256) void caps_kernel(
    const float* __restrict__ xp,   // [B][N][L][16] f32
    const float* __restrict__ wp,   // [K][N][4][4][M] f32
    const float* __restrict__ gp,   // [16] f32
    const float* __restrict__ bp,   // [16] f32
    float* __restrict__ out)        // [B][M][W][16] f32
{
    __shared__ float lw[4 * 32 * 3 * 16];   // 24 KB

    const int tid  = threadIdx.x;
    const int mgrp = blockIdx.y;   // 0..7
    const int b    = blockIdx.z;   // 0..15

    // ---- stage weights to LDS (pre-scaled by 1/32) ----
    for (int idx = tid; idx < 4 * 32 * 3 * 16; idx += 256) {
        int ml   = idx / 1536;
        int rem  = idx - ml * 1536;
        int n    = rem / 48;
        int rem2 = rem - n * 48;
        int k    = rem2 / 16;
        int q    = rem2 - k * 16;        // x*4 + d
        int x4   = q >> 2, d = q & 3;
        int m    = mgrp * 4 + ml;
        int gidx = (((k * 32 + n) * 4 + x4) * 4 + d) * 32 + m;
        lw[idx] = wp[gidx] * 0.03125f;
    }
    __syncthreads();

    const int wl = tid & 63;
    const int ml = tid >> 6;
    const int w  = blockIdx.x * 64 + wl;
    if (w >= W_) return;   // no barriers after this point

    float acc[16];
#pragma unroll
    for (int i = 0; i < 16; ++i) acc[i] = 0.f;

    const float4* lw4 = reinterpret_cast<const float4*>(lw);
    const float*  xb  = xp + (size_t)b * N_ * L_ * D_;

    for (int n = 0; n < N_; ++n) {
        const float* xr = xb + ((size_t)n * L_ + w) * D_;
#pragma unroll
        for (int k = 0; k < K_; ++k) {
            // 16 floats = 64 B, 16B-aligned chunks
            const float4* xv4 = reinterpret_cast<const float4*>(xr + k * D_);
            float xf[16];
#pragma unroll
            for (int i = 0; i < 4; ++i) {
                const float4 r = xv4[i];
                xf[4 * i + 0] = r.x;
                xf[4 * i + 1] = r.y;
                xf[4 * i + 2] = r.z;
                xf[4 * i + 3] = r.w;
            }
            const int base = ((ml * 32 + n) * 3 + k) * 4;   // float4 index
#pragma unroll
            for (int x4 = 0; x4 < 4; ++x4) {
                const float4 wv = lw4[base + x4];
#pragma unroll
                for (int a = 0; a < 4; ++a) {
                    const float xv = xf[a * 4 + x4];
                    acc[a * 4 + 0] += xv * wv.x;
                    acc[a * 4 + 1] += xv * wv.y;
                    acc[a * 4 + 2] += xv * wv.z;
                    acc[a * 4 + 3] += xv * wv.w;
                }
            }
        }
    }

    // ---- fused LayerNorm over the 16-wide last dim ----
    float mu = 0.f;
#pragma unroll
    for (int i = 0; i < 16; ++i) mu += acc[i];
    mu *= (1.f / 16.f);
    float var = 0.f;
#pragma unroll
    for (int i = 0; i < 16; ++i) { float t = acc[i] - mu; var += t * t; }
    var *= (1.f / 16.f);
    const float rstd = rsqrtf(var + 1e-5f);

    const int m = mgrp * 4 + ml;
    float* op = out + (((size_t)(b * M_ + m)) * W_ + w) * D_;
    float4 ov[4];
#pragma unroll
    for (int i = 0; i < 16; ++i) {
        const float g  = gp[i];
        const float be = bp[i];
        const float r  = g * (acc[i] - mu) * rstd + be;
        (&ov[i >> 2].x)[i & 3] = r;
    }
#pragma unroll
    for (int i = 0; i < 4; ++i)
        reinterpret_cast<float4*>(op)[i] = ov[i];
}

extern "C" void kernel_launch(void* const* d_in, const int* in_sizes, int n_in,
                              void* d_out, int out_size, void* d_ws, size_t ws_size,
                              hipStream_t stream) {
    const float* x  = (const float*)d_in[0];
    const float* w  = (const float*)d_in[1];
    const float* g  = (const float*)d_in[2];
    const float* be = (const float*)d_in[3];
    float* out = (float*)d_out;

    dim3 grid((W_ + 63) / 64, M_ / 4, B_);   // (32, 8, 16)
    caps_kernel<<<grid, 256, 0, stream>>>(x, w, g, be, out);
}

// Round 3
// 174.662 us; speedup vs baseline: 2.8983x; 2.8983x over previous
//
#include <hip/hip_runtime.h>
#include <hip/hip_bf16.h>
#include <cstdint>

// Problem dims (fixed by reference)
#define B_  16
#define N_  32
#define L_  2048
#define D_  16
#define M_  32
#define K_  3
#define W_  2046   // (L - K)/STRIDE + 1

typedef __bf16 bf16x8 __attribute__((ext_vector_type(8)));
typedef float  f32x4  __attribute__((ext_vector_type(4)));

union frag_cast { uint4 u; bf16x8 f; };

// pack two fp32 -> one u32 holding two RTNE bf16 (a in low half)
__device__ __forceinline__ uint32_t pk2(float a, float b) {
    __hip_bfloat162 p = __float22bfloat162_rn(make_float2(a, b));
    union { __hip_bfloat162 h; uint32_t u; } cv; cv.h = p; return cv.u;
}

// ---------------------------------------------------------------------------
// Setup: transpose + scale weights into MFMA B-fragment order in d_ws.
// GEMM: K index κ = (k*32 + n)*4 + x  (k-major), col c = m*4 + d.
// ws layout: uint4[ct(8)][kc(12)][lane(64)]; lane's uint4 = 8 bf16 =
// B[κ = kc*32 + (lane>>4)*8 + j][col = ct*16 + (lane&15)], j = 0..7.
// ---------------------------------------------------------------------------
__global__ __launch_bounds__(256) void caps_setup(const float* __restrict__ wp,
                                                  uint4* __restrict__ ws) {
    const int i    = blockIdx.x * 256 + threadIdx.x;   // 0..6143
    const int ct   = i / 768;
    const int rem  = i - ct * 768;
    const int kc   = rem >> 6;
    const int lane = rem & 63;
    const int q    = lane >> 4;
    const int col  = (ct << 4) | (lane & 15);
    const int m = col >> 2, d = col & 3;
    const int k  = kc >> 2;
    const int n0 = (kc & 3) * 8 + q * 2;
    float f[8];
#pragma unroll
    for (int j = 0; j < 8; ++j) {
        const int n = n0 + (j >> 2);
        const int x = j & 3;
        f[j] = wp[(((k * 32 + n) * 4 + x) * 4 + d) * 32 + m] * 0.03125f;
    }
    uint4 o;
    o.x = pk2(f[0], f[1]); o.y = pk2(f[2], f[3]);
    o.z = pk2(f[4], f[5]); o.w = pk2(f[6], f[7]);
    ws[i] = o;
}

// ---------------------------------------------------------------------------
// Main: block = 256 thr = 4 waves; wave owns 64 rows (16 w x 4 a) x 128 cols.
// Grid (32, 16): 512 blocks = 2/CU (launch_bounds(256,2) -> <=256 VGPR).
// A frags straight from global fp32 (cvt in-reg); B frags from d_ws (L2).
// ---------------------------------------------------------------------------
__global__ __launch_bounds__(256, 2) void caps_mfma(
    const float* __restrict__ xp,   // [B][N][L][16]
    const uint4* __restrict__ ws,   // B frags
    const float* __restrict__ gp,   // [16]
    const float* __restrict__ bp,   // [16]
    float* __restrict__ out)        // [B][M][W][16]
{
    const int tid   = threadIdx.x;
    const int wave  = tid >> 6;
    const int lane  = tid & 63;
    const int q     = lane >> 4;        // quad id
    const int l15   = lane & 15;
    const int dL    = lane & 3;         // d (out inner-of-4)
    const int msub  = (lane >> 2) & 3;  // m within col-tile
    const int b     = blockIdx.y;
    const int wbase = blockIdx.x * 64 + wave * 16;

    f32x4 acc[4][8];
#pragma unroll
    for (int rt = 0; rt < 4; ++rt)
#pragma unroll
        for (int ct = 0; ct < 8; ++ct)
            acc[rt][ct] = (f32x4){0.f, 0.f, 0.f, 0.f};

    // A row (lane&15) = wi_sub*4 + a ; clamp padded w (loads stay in-bounds,
    // results masked at store)
    const float* baseA[4];
#pragma unroll
    for (int rt = 0; rt < 4; ++rt) {
        int wv = wbase + rt * 4 + (l15 >> 2);
        if (wv > W_ - 1) wv = W_ - 1;
        baseA[rt] = xp + ((size_t)(b * N_) * L_ + wv) * D_ + (l15 & 3) * 4;
    }

    for (int kc = 0; kc < 12; ++kc) {
        const int k    = kc >> 2;
        const int n0   = (kc & 3) * 8 + q * 2;
        const int off0 = (n0 * L_ + k) * D_;
        const int off1 = off0 + L_ * D_;

        bf16x8 afr[4];
#pragma unroll
        for (int rt = 0; rt < 4; ++rt) {
            const float4 f0 = *reinterpret_cast<const float4*>(baseA[rt] + off0);
            const float4 f1 = *reinterpret_cast<const float4*>(baseA[rt] + off1);
            frag_cast c;
            c.u.x = pk2(f0.x, f0.y); c.u.y = pk2(f0.z, f0.w);
            c.u.z = pk2(f1.x, f1.y); c.u.w = pk2(f1.z, f1.w);
            afr[rt] = c.f;
        }

        const uint4* wsRow = ws + kc * 64 + lane;
#pragma unroll
        for (int ct = 0; ct < 8; ++ct) {
            frag_cast c; c.u = wsRow[ct * 768];
#pragma unroll
            for (int rt = 0; rt < 4; ++rt)
                acc[rt][ct] = __builtin_amdgcn_mfma_f32_16x16x32_bf16(
                    afr[rt], c.f, acc[rt][ct], 0, 0, 0);
        }
    }

    // gamma/beta for this lane's 4 (a = reg r) slots
    float gmv[4], btv[4];
#pragma unroll
    for (int r = 0; r < 4; ++r) { gmv[r] = gp[r * 4 + dL]; btv[r] = bp[r * 4 + dL]; }

    // Fused LayerNorm + store. D layout: row = q*4 + r -> (wi=q, a=r);
    // col = l15 -> (m = ct*4+msub, d = dL). LN group (a,d) = 4 regs x 4 lanes.
#pragma unroll
    for (int rt = 0; rt < 4; ++rt) {
        const int wv = wbase + rt * 4 + q;
#pragma unroll
        for (int ct = 0; ct < 8; ++ct) {
            const f32x4 v = acc[rt][ct];
            float s  = v[0] + v[1] + v[2] + v[3];
            float sq = v[0]*v[0] + v[1]*v[1] + v[2]*v[2] + v[3]*v[3];
            s  += __shfl_xor(s, 1);  s  += __shfl_xor(s, 2);
            sq += __shfl_xor(sq, 1); sq += __shfl_xor(sq, 2);
            const float mu   = s * (1.f / 16.f);
            const float var  = sq * (1.f / 16.f) - mu * mu;
            const float rstd = rsqrtf(var + 1e-5f);
            if (wv < W_) {
                const int m = ct * 4 + msub;
                float* op = out + ((size_t)(b * M_ + m) * W_ + wv) * D_ + dL;
#pragma unroll
                for (int r = 0; r < 4; ++r)
                    op[r * 4] = gmv[r] * (v[r] - mu) * rstd + btv[r];
            }
        }
    }
}

// ---------------------------------------------------------------------------
// Fallback (Round-2 VALU kernel) in case ws_size < 96 KB.
// ---------------------------------------------------------------------------
__global__ __launch_bounds__(256) void caps_fallback(
    const float* __restrict__ xp, const float* __restrict__ wp,
    const float* __restrict__ gp, const float* __restrict__ bp,
    float* __restrict__ out)
{
    __shared__ float lw[4 * 32 * 3 * 16];
    const int tid = threadIdx.x, mgrp = blockIdx.y, b = blockIdx.z;
    for (int idx = tid; idx < 4 * 32 * 3 * 16; idx += 256) {
        int ml = idx / 1536, rem = idx - ml * 1536;
        int n = rem / 48, rem2 = rem - n * 48;
        int k = rem2 / 16, qq = rem2 - k * 16;
        int x4 = qq >> 2, d = qq & 3, m = mgrp * 4 + ml;
        lw[idx] = wp[(((k * 32 + n) * 4 + x4) * 4 + d) * 32 + m] * 0.03125f;
    }
    __syncthreads();
    const int wl = tid & 63, ml = tid >> 6, w = blockIdx.x * 64 + wl;
    if (w >= W_) return;
    float acc[16];
#pragma unroll
    for (int i = 0; i < 16; ++i) acc[i] = 0.f;
    const float4* lw4 = reinterpret_cast<const float4*>(lw);
    const float* xb = xp + (size_t)b * N_ * L_ * D_;
    for (int n = 0; n < N_; ++n) {
        const float* xr = xb + ((size_t)n * L_ + w) * D_;
#pragma unroll
        for (int k = 0; k < K_; ++k) {
            const float4* xv4 = reinterpret_cast<const float4*>(xr + k * D_);
            float xf[16];
#pragma unroll
            for (int i = 0; i < 4; ++i) {
                const float4 r = xv4[i];
                xf[4*i] = r.x; xf[4*i+1] = r.y; xf[4*i+2] = r.z; xf[4*i+3] = r.w;
            }
            const int base = ((ml * 32 + n) * 3 + k) * 4;
#pragma unroll
            for (int x4 = 0; x4 < 4; ++x4) {
                const float4 wv = lw4[base + x4];
#pragma unroll
                for (int a = 0; a < 4; ++a) {
                    const float xv = xf[a * 4 + x4];
                    acc[a*4+0] += xv * wv.x; acc[a*4+1] += xv * wv.y;
                    acc[a*4+2] += xv * wv.z; acc[a*4+3] += xv * wv.w;
                }
            }
        }
    }
    float mu = 0.f;
#pragma unroll
    for (int i = 0; i < 16; ++i) mu += acc[i];
    mu *= (1.f / 16.f);
    float var = 0.f;
#pragma unroll
    for (int i = 0; i < 16; ++i) { float t = acc[i] - mu; var += t * t; }
    var *= (1.f / 16.f);
    const float rstd = rsqrtf(var + 1e-5f);
    const int m = mgrp * 4 + ml;
    float* op = out + (((size_t)(b * M_ + m)) * W_ + w) * D_;
#pragma unroll
    for (int i = 0; i < 16; ++i)
        op[i] = gp[i] * (acc[i] - mu) * rstd + bp[i];
}

extern "C" void kernel_launch(void* const* d_in, const int* in_sizes, int n_in,
                              void* d_out, int out_size, void* d_ws, size_t ws_size,
                              hipStream_t stream) {
    const float* x  = (const float*)d_in[0];
    const float* w  = (const float*)d_in[1];
    const float* g  = (const float*)d_in[2];
    const float* be = (const float*)d_in[3];
    float* out = (float*)d_out;

    if (ws_size >= 6144 * sizeof(uint4)) {
        caps_setup<<<24, 256, 0, stream>>>(w, (uint4*)d_ws);
        caps_mfma<<<dim3(32, 16), 256, 0, stream>>>(
            x, (const uint4*)d_ws, g, be, out);
    } else {
        caps_fallback<<<dim3(32, 8, 16), 256, 0, stream>>>(x, w, g, be, out);
    }
}